// Round 1
// baseline (359.533 us; speedup 1.0000x reference)
//
#include <hip/hip_runtime.h>
#include <cstdint>

#define NN 16
#define W64 64
#define MT 64                    // M elements per workgroup
#define NSTAGE 17                // stage 0 = W1/f, stages 1..16 = graph nodes
#define IST 72                   // inpbuf row stride (halves): 144B, 16B-aligned rows

typedef _Float16 half4   __attribute__((ext_vector_type(4)));
typedef _Float16 half8   __attribute__((ext_vector_type(8)));
typedef _Float16 half16  __attribute__((ext_vector_type(16)));
typedef float    floatx4 __attribute__((ext_vector_type(4)));
typedef unsigned int uint2v __attribute__((ext_vector_type(2)));

// ================== compile-time graph (np.random.RandomState(0)) ==================
// Validated on-device in prior session. Constexpr: masks fold, node tiles get
// live-range-compressed register slots.
struct GPlan {
    unsigned pred[NN];
    unsigned sinkmask;
    int slot[NSTAGE];            // slot[i]: node i (i<16); slot[16] = f
    int nslot;
};

constexpr unsigned mt_next(unsigned (&mt)[624], int &mti) {
    if (mti >= 624) {
        for (int i = 0; i < 624; ++i) {
            const unsigned y = (mt[i] & 0x80000000u) | (mt[(i + 1) % 624] & 0x7fffffffu);
            unsigned v = mt[(i + 397) % 624] ^ (y >> 1);
            if (y & 1u) v ^= 0x9908b0dfu;
            mt[i] = v;
        }
        mti = 0;
    }
    unsigned y = mt[mti++];
    y ^= y >> 11;
    y ^= (y << 7)  & 0x9d2c5680u;
    y ^= (y << 15) & 0xefc60000u;
    y ^= y >> 18;
    return y;
}
constexpr double mt_rnd(unsigned (&mt)[624], int &mti) {
    const unsigned a = mt_next(mt, mti) >> 5;
    const unsigned b = mt_next(mt, mti) >> 6;
    return (a * 67108864.0 + b) / 9007199254740992.0;
}
constexpr long mt_randint(unsigned (&mt)[624], int &mti, long n) {
    const unsigned long maxv = (unsigned long)n - 1;
    if (maxv == 0) return 0;
    unsigned long mask = maxv;
    mask |= mask >> 1;  mask |= mask >> 2;  mask |= mask >> 4;
    mask |= mask >> 8;  mask |= mask >> 16;
    unsigned long v = (unsigned long)mt_next(mt, mti) & mask;
    while (v > maxv) v = (unsigned long)mt_next(mt, mti) & mask;
    return (long)v;
}

constexpr GPlan build_plan() {
    GPlan P = {};
    unsigned mt[624] = {};
    mt[0] = 0u;
    for (int i = 1; i < 624; ++i)
        mt[i] = 1812433253u * (mt[i-1] ^ (mt[i-1] >> 30)) + (unsigned)i;
    int mti = 624;

    bool edge[NN][NN] = {};
    for (int i = 0; i < NN; ++i) {
        for (int d = 1; d <= 2; ++d) {
            int j = (i + d) & (NN - 1);
            if (mt_rnd(mt, mti) < 0.75) j = (int)mt_randint(mt, mti, NN);
            const int a = i < j ? i : j;
            const int b = i < j ? j : i;
            if (a != b) edge[a][b] = true;
        }
    }
    for (int a = 0; a < NN; ++a)
        for (int b = 0; b < NN; ++b)
            if (edge[a][b]) P.pred[b] |= 1u << a;
    for (int j = 1; j < NN; ++j) {
        if (!P.pred[j]) {
            const int a = (int)mt_randint(mt, mti, j);
            P.pred[j] |= 1u << a;
            edge[a][j] = true;
        }
    }
    unsigned succ[NN] = {};
    for (int a = 0; a < NN; ++a)
        for (int b = 0; b < NN; ++b)
            if (edge[a][b]) succ[a] |= 1u << b;
    for (int j = 0; j < NN; ++j)
        if (!succ[j]) P.sinkmask |= 1u << j;

    int lastuse[NSTAGE] = {};
    for (int v = 0; v < NSTAGE; ++v) lastuse[v] = -1;
    for (int j = 0; j < NN; ++j) {
        const unsigned pm = P.pred[j];
        if (pm == 0u) { if (j > lastuse[16]) lastuse[16] = j; }
        else for (int i = 0; i < NN; ++i)
            if (pm & (1u << i)) { if (j > lastuse[i]) lastuse[i] = j; }
    }
    for (int i = 0; i < NN; ++i)
        if (P.sinkmask & (1u << i)) lastuse[i] = 17;

    int defstage[NSTAGE] = {};
    for (int i = 0; i < NN; ++i) defstage[i] = i + 1;
    defstage[16] = 0;

    int nmax = 0;
    for (int s = 0; s <= 16; ++s) {
        const int w = (s == 0) ? 16 : (s - 1);
        bool busy[NSTAGE] = {};
        for (int v = 0; v < NSTAGE; ++v) {
            if (v == w) continue;
            if (defstage[v] < s && lastuse[v] >= s)
                busy[P.slot[v]] = true;
        }
        int k = 0;
        while (busy[k]) ++k;
        P.slot[w] = k;
        if (k + 1 > nmax) nmax = k + 1;
    }
    P.nslot = nmax;
    return P;
}

constexpr GPlan kPlan = build_plan();
constexpr int NSLOT = kPlan.nslot;

// ---------------- fast activations ----------------
__device__ __forceinline__ float act_tanh(float x)     { return 1.0f - 2.0f / (1.0f + __expf(2.0f * x)); }
__device__ __forceinline__ float act_elu(float x)      { return x > 0.0f ? x : __expf(x) - 1.0f; }
__device__ __forceinline__ float act_softplus(float x) { return fmaxf(x, 0.0f) + __logf(1.0f + __expf(-fabsf(x))); }
__device__ __forceinline__ float act_gauss(float x)    { return __expf(-0.5f * x * x); }

__device__ __forceinline__ float apply_act(int a, float x) {
    switch (a) {
        case 0:  return act_tanh(x);
        case 1:  return act_elu(x);
        case 2:  return act_softplus(x);
        case 3:  return __sinf(x);
        default: return act_gauss(x);
    }
}

__device__ __forceinline__ half8 cvt8(float4 a, float4 b) {
    half8 h;
    h[0]=(_Float16)a.x; h[1]=(_Float16)a.y; h[2]=(_Float16)a.z; h[3]=(_Float16)a.w;
    h[4]=(_Float16)b.x; h[5]=(_Float16)b.y; h[6]=(_Float16)b.z; h[7]=(_Float16)b.w;
    return h;
}

// ---------------- weight pre-conversion: fp32 -> fp16 into d_ws ----------------
// ws layout: stage 0 = W1[64][64], stage 1+j = gW[j][64][64]; [w'][k] row-major.
__global__ void convert_weights(const float* __restrict__ W1,
                                const float* __restrict__ gW,
                                _Float16* __restrict__ ws)
{
    const int i = blockIdx.x * 256 + threadIdx.x;
    if (i >= NSTAGE * 4096) return;
    const float v = (i < 4096) ? W1[i] : gW[i - 4096];
    ws[i] = (_Float16)v;
}

// ---------------- main fused kernel ----------------
// BARRIER-FREE restructure:
//  * MFMA operands SWAPPED vs previous version: acc[t] = mfma(W_frag, inp_frag).
//    D = H^T layout: lane(q,c) holds H[m = rowbase+c][w' = t*16 + q*4 + r].
//    -> next-stage input write is 4x ds_write_b64 straight from packed fp16 regs
//       (was 16x ds_write_b16), and bias folds per-reg as a float4 acc init.
//  * Weights are read per-wave straight from global (wsW, 139KB, L1/L2-hot) as
//    the MFMA A-fragment: half8 at wsW[s*4096 + (t*16+c)*64 + q*8] (+32).
//    This removes wbuf entirely -> NO cross-wave shared LDS -> ZERO __syncthreads.
//  * inpbuf rows are wave-private (reads rowbase..rowbase+15 == writes); same-wave
//    DS ordering is in-order, compiler inserts lgkmcnt as needed.
//  * Head is all-register: reduce over q-lanes via __shfl_xor(16/32), no LDS trip.
template<bool F16W>
__global__ __launch_bounds__(256, 4) void inr_mfma_kernel(
    const float* __restrict__ inputs, const float* __restrict__ latents,
    const float* __restrict__ Wl, const float* __restrict__ bl,
    const float* __restrict__ Wx, const float* __restrict__ Wy,
    const float* __restrict__ Wr, const float* __restrict__ W1,
    const float* __restrict__ b1, const float* __restrict__ gW,
    const float* __restrict__ gB, const float* __restrict__ outW,
    const float* __restrict__ outb, const float* __restrict__ scale,
    const _Float16* __restrict__ wsW,
    float* __restrict__ out, int Btot)
{
    __shared__ __align__(16) _Float16 inpbuf[MT * IST];   // 9216 B, wave-private rows

    const int tid  = threadIdx.x;
    const int lane = tid & 63;
    const int wv   = tid >> 6;            // wave id 0..3
    const int q    = lane >> 4;           // quad
    const int c    = lane & 15;           // col-in-tile (= m-row index in new layout)
    const int rowbase = wv * 16;          // this wave's 16 M-rows within the tile
    const int m0   = blockIdx.x * MT;

    // node state, slot-compressed. New layout:
    // hreg[slot][t*4+r] = h_n[m = rowbase+c][w' = t*16 + q*4 + r]
    half16 hreg[NSLOT];

    // ---- embed: g0[m][k] -> inpbuf  (thread t: m = t>>2, k-range = (t&3)*16..+15)
    {
        const int em = tid >> 2, ep = tid & 3;
        int mg = m0 + em; if (mg >= Btot) mg = Btot - 1;
        const float x = inputs[mg * 3 + 0];
        const float y = inputs[mg * 3 + 1];
        const float r = inputs[mg * 3 + 2];
        const float4 l0 = *(const float4*)(latents + mg * 8);
        const float4 l1 = *(const float4*)(latents + mg * 8 + 4);
        half8 hlo, hhi;
        #pragma unroll
        for (int i = 0; i < 16; ++i) {
            const int k = ep * 16 + i;
            const float4 a = *(const float4*)(Wl + k * 8);
            const float4 b = *(const float4*)(Wl + k * 8 + 4);
            float ld = bl[k];
            ld = fmaf(l0.x, a.x, ld); ld = fmaf(l0.y, a.y, ld);
            ld = fmaf(l0.z, a.z, ld); ld = fmaf(l0.w, a.w, ld);
            ld = fmaf(l1.x, b.x, ld); ld = fmaf(l1.y, b.y, ld);
            ld = fmaf(l1.z, b.z, ld); ld = fmaf(l1.w, b.w, ld);
            const float tk = act_tanh(x * Wx[k]) + act_softplus(y * Wy[k])
                           + act_elu(r * Wr[k]) + act_tanh(ld);
            const _Float16 hv = (_Float16)act_gauss(tk);
            if (i < 8) hlo[i] = hv; else hhi[i - 8] = hv;
        }
        *(half8*)&inpbuf[em * IST + ep * 16]     = hlo;   // 2x ds_write_b128
        *(half8*)&inpbuf[em * IST + ep * 16 + 8] = hhi;
    }
    // no barrier: rows em are this wave's own rows, DS ops are in-order per wave

    // ---- stage loop (no barriers anywhere) ----
    #pragma unroll
    for (int s = 0; s < NSTAGE; ++s) {
        // input B-fragments: B[k][n] = inp[rowbase+n][k]; lane provides
        // inp[rowbase+c][q*8+j] (lo) and inp[rowbase+c][32+q*8+j] (hi)
        const half8 i0 = *(const half8*)&inpbuf[(rowbase + c) * IST +  0 + q * 8];
        const half8 i1 = *(const half8*)&inpbuf[(rowbase + c) * IST + 32 + q * 8];

        const float* bias = (s == 0) ? b1 : (gB + (s - 1) * W64);

        floatx4 acc[4];
        #pragma unroll
        for (int t = 0; t < 4; ++t) {
            // A-fragments = weight rows, straight from global (L1/L2-hot):
            // A[i][k] = W[t*16+i][k]; lane holds row t*16+c, k = q*8..q*8+7 (+32)
            half8 wlo, whi;
            if constexpr (F16W) {
                const _Float16* wr = wsW + s * 4096 + (t * 16 + c) * 64 + q * 8;
                wlo = *(const half8*)wr;
                whi = *(const half8*)(wr + 32);
            } else {
                const float* wr = ((s == 0) ? W1 : (gW + (s - 1) * 4096))
                                  + (t * 16 + c) * 64 + q * 8;
                wlo = cvt8(*(const float4*)wr,        *(const float4*)(wr + 4));
                whi = cvt8(*(const float4*)(wr + 32), *(const float4*)(wr + 36));
            }
            // bias varies per-reg now: row i = q*4+r -> bias[t*16+q*4+r], one float4
            const float4 bs = *(const float4*)(bias + t * 16 + q * 4);
            floatx4 z = {bs.x, bs.y, bs.z, bs.w};
            z = __builtin_amdgcn_mfma_f32_16x16x32_f16(wlo, i0, z, 0, 0, 0);
            z = __builtin_amdgcn_mfma_f32_16x16x32_f16(whi, i1, z, 0, 0, 0);
            acc[t] = z;
        }

        // epilogue: activation -> hreg slot (H^T layout, packed)
        const int an    = (s == 0) ? 3 : ((s - 1) % 5);        // stage0 act = sin
        const int hslot = kPlan.slot[(s == 0) ? 16 : (s - 1)]; // constexpr-folds
        #pragma unroll
        for (int t = 0; t < 4; ++t) {
            #pragma unroll
            for (int r = 0; r < 4; ++r) {
                const float v = apply_act(an, acc[t][r]);
                hreg[hslot][t * 4 + r] = (_Float16)v;
            }
        }

        // build next stage's input (packed fp16 pred-sum, masks fold statically)
        if (s + 1 < NSTAGE) {
            const unsigned pm = kPlan.pred[s];    // compile-time constant
            half16 sum;
            if (pm == 0u) {                       // source: input = f
                sum = hreg[kPlan.slot[16]];
            } else {
                #pragma unroll
                for (int v = 0; v < 16; ++v) sum[v] = (_Float16)0.0f;
                #pragma unroll
                for (int i = 0; i < NN; ++i) {
                    if (pm & (1u << i)) {         // dead branches removed
                        sum += hreg[kPlan.slot[i]];
                    }
                }
            }
            // lane(q,c) owns w' = t*16+q*4..+3 of row rowbase+c: 4 consecutive
            // halves = one ds_write_b64 per t, straight from sum's reg pairs.
            const uint2v* sp = (const uint2v*)&sum;
            #pragma unroll
            for (int t = 0; t < 4; ++t)
                *(uint2v*)&inpbuf[(rowbase + c) * IST + t * 16 + q * 4] = sp[t];
            // no barrier: same-wave RAW through LDS, in-order per wave
        }
    }

    // ---- head: agg over sinks in-register, reduce over q-lanes, sigmoid ----
    {
        half16 sum;
        #pragma unroll
        for (int v = 0; v < 16; ++v) sum[v] = (_Float16)0.0f;
        #pragma unroll
        for (int j = 0; j < NN; ++j) {
            if (kPlan.sinkmask & (1u << j)) {     // folds statically
                sum += hreg[kPlan.slot[j]];
            }
        }
        float p0 = 0.f, p1 = 0.f, p2 = 0.f;
        #pragma unroll
        for (int t = 0; t < 4; ++t) {
            const float4 w0 = *(const float4*)(outW + 0 * W64 + t * 16 + q * 4);
            const float4 w1 = *(const float4*)(outW + 1 * W64 + t * 16 + q * 4);
            const float4 w2 = *(const float4*)(outW + 2 * W64 + t * 16 + q * 4);
            #pragma unroll
            for (int r = 0; r < 4; ++r) {
                const float av = (float)sum[t * 4 + r];
                p0 = fmaf(av, ((const float*)&w0)[r], p0);
                p1 = fmaf(av, ((const float*)&w1)[r], p1);
                p2 = fmaf(av, ((const float*)&w2)[r], p2);
            }
        }
        // full dot for row m = rowbase+c lives across lanes c, c+16, c+32, c+48
        p0 += __shfl_xor(p0, 16); p0 += __shfl_xor(p0, 32);
        p1 += __shfl_xor(p1, 16); p1 += __shfl_xor(p1, 32);
        p2 += __shfl_xor(p2, 16); p2 += __shfl_xor(p2, 32);
        const int mg = m0 + rowbase + c;
        if (q < 3 && mg < Btot) {
            const float pr  = (q == 0) ? p0 : ((q == 1) ? p1 : p2);
            const float res = (pr + outb[q]) * scale[0];
            out[mg * 3 + q] = 1.0f / (1.0f + __expf(-res));
        }
    }
}

extern "C" void kernel_launch(void* const* d_in, const int* in_sizes, int n_in,
                              void* d_out, int out_size, void* d_ws, size_t ws_size,
                              hipStream_t stream)
{
    const float* inputs  = (const float*)d_in[0];
    const float* latents = (const float*)d_in[1];
    const float* Wl      = (const float*)d_in[2];
    const float* bl      = (const float*)d_in[3];
    const float* Wx      = (const float*)d_in[4];
    const float* Wy      = (const float*)d_in[5];
    const float* Wr      = (const float*)d_in[6];
    const float* W1      = (const float*)d_in[7];
    const float* b1      = (const float*)d_in[8];
    const float* gW      = (const float*)d_in[9];
    const float* gB      = (const float*)d_in[10];
    const float* outW    = (const float*)d_in[11];
    const float* outb    = (const float*)d_in[12];
    const float* scale   = (const float*)d_in[13];
    float* out = (float*)d_out;

    const int Btot = in_sizes[0] / 3;
    const int blocks = (Btot + MT - 1) / MT;
    const size_t wbytes = (size_t)NSTAGE * 4096 * sizeof(_Float16);  // 139264

    if (ws_size >= wbytes) {
        _Float16* wsW = (_Float16*)d_ws;
        convert_weights<<<(NSTAGE * 4096 + 255) / 256, 256, 0, stream>>>(W1, gW, wsW);
        inr_mfma_kernel<true><<<blocks, 256, 0, stream>>>(
            inputs, latents, Wl, bl, Wx, Wy, Wr, W1, b1, gW, gB, outW, outb, scale,
            wsW, out, Btot);
    } else {
        inr_mfma_kernel<false><<<blocks, 256, 0, stream>>>(
            inputs, latents, Wl, bl, Wx, Wy, Wr, W1, b1, gW, gB, outW, outb, scale,
            (const _Float16*)nullptr, out, Btot);
    }
}

// Round 2
// 258.368 us; speedup vs baseline: 1.3916x; 1.3916x over previous
//
#include <hip/hip_runtime.h>
#include <cstdint>

#define NN 16
#define W64 64
#define MT 64                    // M elements per workgroup
#define NSTAGE 17                // stage 0 = W1/f, stages 1..16 = graph nodes
#define IST 72                   // inpbuf row stride (halves): 144B, 16B-aligned rows

typedef _Float16 half4   __attribute__((ext_vector_type(4)));
typedef _Float16 half8   __attribute__((ext_vector_type(8)));
typedef _Float16 half16  __attribute__((ext_vector_type(16)));
typedef float    floatx4 __attribute__((ext_vector_type(4)));
typedef unsigned int uint2v __attribute__((ext_vector_type(2)));

// ================== compile-time graph (np.random.RandomState(0)) ==================
// Validated on-device in prior session. Constexpr: masks fold, node tiles get
// live-range-compressed register slots.
struct GPlan {
    unsigned pred[NN];
    unsigned sinkmask;
    int slot[NSTAGE];            // slot[i]: node i (i<16); slot[16] = f
    int nslot;
};

constexpr unsigned mt_next(unsigned (&mt)[624], int &mti) {
    if (mti >= 624) {
        for (int i = 0; i < 624; ++i) {
            const unsigned y = (mt[i] & 0x80000000u) | (mt[(i + 1) % 624] & 0x7fffffffu);
            unsigned v = mt[(i + 397) % 624] ^ (y >> 1);
            if (y & 1u) v ^= 0x9908b0dfu;
            mt[i] = v;
        }
        mti = 0;
    }
    unsigned y = mt[mti++];
    y ^= y >> 11;
    y ^= (y << 7)  & 0x9d2c5680u;
    y ^= (y << 15) & 0xefc60000u;
    y ^= y >> 18;
    return y;
}
constexpr double mt_rnd(unsigned (&mt)[624], int &mti) {
    const unsigned a = mt_next(mt, mti) >> 5;
    const unsigned b = mt_next(mt, mti) >> 6;
    return (a * 67108864.0 + b) / 9007199254740992.0;
}
constexpr long mt_randint(unsigned (&mt)[624], int &mti, long n) {
    const unsigned long maxv = (unsigned long)n - 1;
    if (maxv == 0) return 0;
    unsigned long mask = maxv;
    mask |= mask >> 1;  mask |= mask >> 2;  mask |= mask >> 4;
    mask |= mask >> 8;  mask |= mask >> 16;
    unsigned long v = (unsigned long)mt_next(mt, mti) & mask;
    while (v > maxv) v = (unsigned long)mt_next(mt, mti) & mask;
    return (long)v;
}

constexpr GPlan build_plan() {
    GPlan P = {};
    unsigned mt[624] = {};
    mt[0] = 0u;
    for (int i = 1; i < 624; ++i)
        mt[i] = 1812433253u * (mt[i-1] ^ (mt[i-1] >> 30)) + (unsigned)i;
    int mti = 624;

    bool edge[NN][NN] = {};
    for (int i = 0; i < NN; ++i) {
        for (int d = 1; d <= 2; ++d) {
            int j = (i + d) & (NN - 1);
            if (mt_rnd(mt, mti) < 0.75) j = (int)mt_randint(mt, mti, NN);
            const int a = i < j ? i : j;
            const int b = i < j ? j : i;
            if (a != b) edge[a][b] = true;
        }
    }
    for (int a = 0; a < NN; ++a)
        for (int b = 0; b < NN; ++b)
            if (edge[a][b]) P.pred[b] |= 1u << a;
    for (int j = 1; j < NN; ++j) {
        if (!P.pred[j]) {
            const int a = (int)mt_randint(mt, mti, j);
            P.pred[j] |= 1u << a;
            edge[a][j] = true;
        }
    }
    unsigned succ[NN] = {};
    for (int a = 0; a < NN; ++a)
        for (int b = 0; b < NN; ++b)
            if (edge[a][b]) succ[a] |= 1u << b;
    for (int j = 0; j < NN; ++j)
        if (!succ[j]) P.sinkmask |= 1u << j;

    int lastuse[NSTAGE] = {};
    for (int v = 0; v < NSTAGE; ++v) lastuse[v] = -1;
    for (int j = 0; j < NN; ++j) {
        const unsigned pm = P.pred[j];
        if (pm == 0u) { if (j > lastuse[16]) lastuse[16] = j; }
        else for (int i = 0; i < NN; ++i)
            if (pm & (1u << i)) { if (j > lastuse[i]) lastuse[i] = j; }
    }
    for (int i = 0; i < NN; ++i)
        if (P.sinkmask & (1u << i)) lastuse[i] = 17;

    int defstage[NSTAGE] = {};
    for (int i = 0; i < NN; ++i) defstage[i] = i + 1;
    defstage[16] = 0;

    int nmax = 0;
    for (int s = 0; s <= 16; ++s) {
        const int w = (s == 0) ? 16 : (s - 1);
        bool busy[NSTAGE] = {};
        for (int v = 0; v < NSTAGE; ++v) {
            if (v == w) continue;
            if (defstage[v] < s && lastuse[v] >= s)
                busy[P.slot[v]] = true;
        }
        int k = 0;
        while (busy[k]) ++k;
        P.slot[w] = k;
        if (k + 1 > nmax) nmax = k + 1;
    }
    P.nslot = nmax;
    return P;
}

constexpr GPlan kPlan = build_plan();
constexpr int NSLOT = kPlan.nslot;

// ---------------- fast activations ----------------
__device__ __forceinline__ float act_tanh(float x)     { return 1.0f - 2.0f / (1.0f + __expf(2.0f * x)); }
__device__ __forceinline__ float act_elu(float x)      { return x > 0.0f ? x : __expf(x) - 1.0f; }
__device__ __forceinline__ float act_softplus(float x) { return fmaxf(x, 0.0f) + __logf(1.0f + __expf(-fabsf(x))); }
__device__ __forceinline__ float act_gauss(float x)    { return __expf(-0.5f * x * x); }

// compile-time activation dispatch (no runtime switch anywhere)
template<int A>
__device__ __forceinline__ float act_c(float x) {
    if constexpr (A == 0)      return act_tanh(x);
    else if constexpr (A == 1) return act_elu(x);
    else if constexpr (A == 2) return act_softplus(x);
    else if constexpr (A == 3) return __sinf(x);
    else                       return act_gauss(x);
}

__device__ __forceinline__ half8 cvt8(float4 a, float4 b) {
    half8 h;
    h[0]=(_Float16)a.x; h[1]=(_Float16)a.y; h[2]=(_Float16)a.z; h[3]=(_Float16)a.w;
    h[4]=(_Float16)b.x; h[5]=(_Float16)b.y; h[6]=(_Float16)b.z; h[7]=(_Float16)b.w;
    return h;
}

// ---------------- weight pre-conversion: fp32 -> fp16 into d_ws ----------------
// ws layout: stage 0 = W1[64][64], stage 1+j = gW[j][64][64]; [w'][k] row-major.
__global__ void convert_weights(const float* __restrict__ W1,
                                const float* __restrict__ gW,
                                _Float16* __restrict__ ws)
{
    const int i = blockIdx.x * 256 + threadIdx.x;
    if (i >= NSTAGE * 4096) return;
    const float v = (i < 4096) ? W1[i] : gW[i - 4096];
    ws[i] = (_Float16)v;
}

// ---------------- one fully-static stage ----------------
// Round-1 post-mortem: '#pragma unroll' on the 17-stage loop silently failed
// (body too large) -> runtime s -> hreg[] dynamically indexed -> demoted to
// scratch (VGPR 32, 0.5 GB scratch traffic, 294us). Fix: S is a template
// parameter, 17 explicit instantiations. Every kPlan access / slot index /
// activation selector is now a bona-fide constant expression.
template<bool F16W, int S>
__device__ __forceinline__ void do_stage(
    _Float16* __restrict__ inpbuf, half16* hreg,
    const _Float16* __restrict__ wsW,
    const float* __restrict__ W1, const float* __restrict__ gW,
    const float* __restrict__ b1, const float* __restrict__ gB,
    const int rowbase, const int c, const int q)
{
    // input B-fragments: B[k][n] = inp[rowbase+n][k]; lane supplies
    // inp[rowbase+c][q*8+j] (lo) and inp[rowbase+c][32+q*8+j] (hi)
    const half8 i0 = *(const half8*)&inpbuf[(rowbase + c) * IST +  0 + q * 8];
    const half8 i1 = *(const half8*)&inpbuf[(rowbase + c) * IST + 32 + q * 8];

    const float* bias;
    if constexpr (S == 0) bias = b1; else bias = gB + (S - 1) * W64;

    floatx4 acc[4];
    #pragma unroll
    for (int t = 0; t < 4; ++t) {
        // A-fragments = weight rows, straight from global (L1/L2-hot):
        // A[i][k] = W[t*16+i][k]; lane holds row t*16+c, k = q*8..q*8+7 (+32)
        half8 wlo, whi;
        if constexpr (F16W) {
            const _Float16* wr = wsW + S * 4096 + (t * 16 + c) * 64 + q * 8;
            wlo = *(const half8*)wr;
            whi = *(const half8*)(wr + 32);
        } else {
            const float* wbase;
            if constexpr (S == 0) wbase = W1; else wbase = gW + (S - 1) * 4096;
            const float* wr = wbase + (t * 16 + c) * 64 + q * 8;
            wlo = cvt8(*(const float4*)wr,        *(const float4*)(wr + 4));
            whi = cvt8(*(const float4*)(wr + 32), *(const float4*)(wr + 36));
        }
        // bias varies per-reg: row i = q*4+r -> bias[t*16+q*4+r], one float4
        const float4 bs = *(const float4*)(bias + t * 16 + q * 4);
        floatx4 z = {bs.x, bs.y, bs.z, bs.w};
        z = __builtin_amdgcn_mfma_f32_16x16x32_f16(wlo, i0, z, 0, 0, 0);
        z = __builtin_amdgcn_mfma_f32_16x16x32_f16(whi, i1, z, 0, 0, 0);
        acc[t] = z;
    }

    // epilogue: activation -> hreg slot (H^T layout, packed); all indices constexpr
    constexpr int an    = (S == 0) ? 3 : ((S - 1) % 5);        // stage0 act = sin
    constexpr int hslot = kPlan.slot[(S == 0) ? 16 : (S - 1)];
    #pragma unroll
    for (int t = 0; t < 4; ++t)
        #pragma unroll
        for (int r = 0; r < 4; ++r)
            hreg[hslot][t * 4 + r] = (_Float16)act_c<an>(acc[t][r]);

    // build next stage's input (packed fp16 pred-sum, masks fold statically)
    if constexpr (S + 1 < NSTAGE) {
        constexpr unsigned pm = kPlan.pred[S];
        half16 sum;
        if constexpr (pm == 0u) {                 // source: input = f
            sum = hreg[kPlan.slot[16]];
        } else {
            #pragma unroll
            for (int v = 0; v < 16; ++v) sum[v] = (_Float16)0.0f;
            #pragma unroll
            for (int i = 0; i < NN; ++i)
                if (pm & (1u << i))               // dead branches removed
                    sum += hreg[kPlan.slot[i]];
        }
        // lane(q,c) owns w' = t*16+q*4..+3 of row rowbase+c: 4 consecutive
        // halves = one ds_write_b64 per t, straight from sum's reg pairs.
        const uint2v* sp = (const uint2v*)&sum;
        #pragma unroll
        for (int t = 0; t < 4; ++t)
            *(uint2v*)&inpbuf[(rowbase + c) * IST + t * 16 + q * 4] = sp[t];
        // no barrier: same-wave RAW through LDS, in-order per wave
    }
}

// ---------------- main fused kernel (barrier-free) ----------------
//  * acc[t] = mfma(W_frag, inp_frag): D = H^T layout, lane(q,c) holds
//    H[m = rowbase+c][w' = t*16 + q*4 + r] -> next-stage write is 4x ds_write_b64.
//  * Weights read per-wave from global (wsW, 139KB, L1/L2-hot) as the A-fragment.
//    No shared wbuf -> no cross-wave LDS coupling -> ZERO __syncthreads.
//  * inpbuf rows are wave-private; same-wave DS ordering is in-order.
//  * launch_bounds (256,3): VGPR headroom so cross-stage hoisting can't spill.
template<bool F16W>
__global__ __launch_bounds__(256, 3) void inr_mfma_kernel(
    const float* __restrict__ inputs, const float* __restrict__ latents,
    const float* __restrict__ Wl, const float* __restrict__ bl,
    const float* __restrict__ Wx, const float* __restrict__ Wy,
    const float* __restrict__ Wr, const float* __restrict__ W1,
    const float* __restrict__ b1, const float* __restrict__ gW,
    const float* __restrict__ gB, const float* __restrict__ outW,
    const float* __restrict__ outb, const float* __restrict__ scale,
    const _Float16* __restrict__ wsW,
    float* __restrict__ out, int Btot)
{
    __shared__ __align__(16) _Float16 inpbuf[MT * IST];   // 9216 B, wave-private rows

    const int tid  = threadIdx.x;
    const int lane = tid & 63;
    const int wv   = tid >> 6;            // wave id 0..3
    const int q    = lane >> 4;           // quad
    const int c    = lane & 15;           // col-in-tile (= m-row index)
    const int rowbase = wv * 16;          // this wave's 16 M-rows within the tile
    const int m0   = blockIdx.x * MT;

    // node state, slot-compressed:
    // hreg[slot][t*4+r] = h_n[m = rowbase+c][w' = t*16 + q*4 + r]
    half16 hreg[NSLOT];

    // ---- embed: g0[m][k] -> inpbuf  (thread t: m = t>>2, k-range = (t&3)*16..+15)
    {
        const int em = tid >> 2, ep = tid & 3;
        int mg = m0 + em; if (mg >= Btot) mg = Btot - 1;
        const float x = inputs[mg * 3 + 0];
        const float y = inputs[mg * 3 + 1];
        const float r = inputs[mg * 3 + 2];
        const float4 l0 = *(const float4*)(latents + mg * 8);
        const float4 l1 = *(const float4*)(latents + mg * 8 + 4);
        half8 hlo, hhi;
        #pragma unroll
        for (int i = 0; i < 16; ++i) {
            const int k = ep * 16 + i;
            const float4 a = *(const float4*)(Wl + k * 8);
            const float4 b = *(const float4*)(Wl + k * 8 + 4);
            float ld = bl[k];
            ld = fmaf(l0.x, a.x, ld); ld = fmaf(l0.y, a.y, ld);
            ld = fmaf(l0.z, a.z, ld); ld = fmaf(l0.w, a.w, ld);
            ld = fmaf(l1.x, b.x, ld); ld = fmaf(l1.y, b.y, ld);
            ld = fmaf(l1.z, b.z, ld); ld = fmaf(l1.w, b.w, ld);
            const float tk = act_tanh(x * Wx[k]) + act_softplus(y * Wy[k])
                           + act_elu(r * Wr[k]) + act_tanh(ld);
            const _Float16 hv = (_Float16)act_gauss(tk);
            if (i < 8) hlo[i] = hv; else hhi[i - 8] = hv;
        }
        *(half8*)&inpbuf[em * IST + ep * 16]     = hlo;   // 2x ds_write_b128
        *(half8*)&inpbuf[em * IST + ep * 16 + 8] = hhi;
    }
    // no barrier: rows em are this wave's own rows, DS ops in-order per wave

    // ---- stage chain: 17 explicit instantiations, S is a template constant ----
    _Float16* ib = &inpbuf[0];
    do_stage<F16W,  0>(ib, hreg, wsW, W1, gW, b1, gB, rowbase, c, q);
    do_stage<F16W,  1>(ib, hreg, wsW, W1, gW, b1, gB, rowbase, c, q);
    do_stage<F16W,  2>(ib, hreg, wsW, W1, gW, b1, gB, rowbase, c, q);
    do_stage<F16W,  3>(ib, hreg, wsW, W1, gW, b1, gB, rowbase, c, q);
    do_stage<F16W,  4>(ib, hreg, wsW, W1, gW, b1, gB, rowbase, c, q);
    do_stage<F16W,  5>(ib, hreg, wsW, W1, gW, b1, gB, rowbase, c, q);
    do_stage<F16W,  6>(ib, hreg, wsW, W1, gW, b1, gB, rowbase, c, q);
    do_stage<F16W,  7>(ib, hreg, wsW, W1, gW, b1, gB, rowbase, c, q);
    do_stage<F16W,  8>(ib, hreg, wsW, W1, gW, b1, gB, rowbase, c, q);
    do_stage<F16W,  9>(ib, hreg, wsW, W1, gW, b1, gB, rowbase, c, q);
    do_stage<F16W, 10>(ib, hreg, wsW, W1, gW, b1, gB, rowbase, c, q);
    do_stage<F16W, 11>(ib, hreg, wsW, W1, gW, b1, gB, rowbase, c, q);
    do_stage<F16W, 12>(ib, hreg, wsW, W1, gW, b1, gB, rowbase, c, q);
    do_stage<F16W, 13>(ib, hreg, wsW, W1, gW, b1, gB, rowbase, c, q);
    do_stage<F16W, 14>(ib, hreg, wsW, W1, gW, b1, gB, rowbase, c, q);
    do_stage<F16W, 15>(ib, hreg, wsW, W1, gW, b1, gB, rowbase, c, q);
    do_stage<F16W, 16>(ib, hreg, wsW, W1, gW, b1, gB, rowbase, c, q);

    // ---- head: agg over sinks in-register, reduce over q-lanes, sigmoid ----
    {
        half16 sum;
        #pragma unroll
        for (int v = 0; v < 16; ++v) sum[v] = (_Float16)0.0f;
        #pragma unroll
        for (int j = 0; j < NN; ++j) {
            if (kPlan.sinkmask & (1u << j)) {     // folds statically
                sum += hreg[kPlan.slot[j]];
            }
        }
        float p0 = 0.f, p1 = 0.f, p2 = 0.f;
        #pragma unroll
        for (int t = 0; t < 4; ++t) {
            const float4 w0 = *(const float4*)(outW + 0 * W64 + t * 16 + q * 4);
            const float4 w1 = *(const float4*)(outW + 1 * W64 + t * 16 + q * 4);
            const float4 w2 = *(const float4*)(outW + 2 * W64 + t * 16 + q * 4);
            #pragma unroll
            for (int r = 0; r < 4; ++r) {
                const float av = (float)sum[t * 4 + r];
                p0 = fmaf(av, ((const float*)&w0)[r], p0);
                p1 = fmaf(av, ((const float*)&w1)[r], p1);
                p2 = fmaf(av, ((const float*)&w2)[r], p2);
            }
        }
        // full dot for row m = rowbase+c lives across lanes c, c+16, c+32, c+48
        p0 += __shfl_xor(p0, 16); p0 += __shfl_xor(p0, 32);
        p1 += __shfl_xor(p1, 16); p1 += __shfl_xor(p1, 32);
        p2 += __shfl_xor(p2, 16); p2 += __shfl_xor(p2, 32);
        const int mg = m0 + rowbase + c;
        if (q < 3 && mg < Btot) {
            const float pr  = (q == 0) ? p0 : ((q == 1) ? p1 : p2);
            const float res = (pr + outb[q]) * scale[0];
            out[mg * 3 + q] = 1.0f / (1.0f + __expf(-res));
        }
    }
}

extern "C" void kernel_launch(void* const* d_in, const int* in_sizes, int n_in,
                              void* d_out, int out_size, void* d_ws, size_t ws_size,
                              hipStream_t stream)
{
    const float* inputs  = (const float*)d_in[0];
    const float* latents = (const float*)d_in[1];
    const float* Wl      = (const float*)d_in[2];
    const float* bl      = (const float*)d_in[3];
    const float* Wx      = (const float*)d_in[4];
    const float* Wy      = (const float*)d_in[5];
    const float* Wr      = (const float*)d_in[6];
    const float* W1      = (const float*)d_in[7];
    const float* b1      = (const float*)d_in[8];
    const float* gW      = (const float*)d_in[9];
    const float* gB      = (const float*)d_in[10];
    const float* outW    = (const float*)d_in[11];
    const float* outb    = (const float*)d_in[12];
    const float* scale   = (const float*)d_in[13];
    float* out = (float*)d_out;

    const int Btot = in_sizes[0] / 3;
    const int blocks = (Btot + MT - 1) / MT;
    const size_t wbytes = (size_t)NSTAGE * 4096 * sizeof(_Float16);  // 139264

    if (ws_size >= wbytes) {
        _Float16* wsW = (_Float16*)d_ws;
        convert_weights<<<(NSTAGE * 4096 + 255) / 256, 256, 0, stream>>>(W1, gW, wsW);
        inr_mfma_kernel<true><<<blocks, 256, 0, stream>>>(
            inputs, latents, Wl, bl, Wx, Wy, Wr, W1, b1, gW, gB, outW, outb, scale,
            wsW, out, Btot);
    } else {
        inr_mfma_kernel<false><<<blocks, 256, 0, stream>>>(
            inputs, latents, Wl, bl, Wx, Wy, Wr, W1, b1, gW, gB, outW, outb, scale,
            (const _Float16*)nullptr, out, Btot);
    }
}

// Round 3
// 254.982 us; speedup vs baseline: 1.4100x; 1.0133x over previous
//
#include <hip/hip_runtime.h>
#include <cstdint>

#define NN 16
#define W64 64
#define MT 64                    // M elements per workgroup
#define NSTAGE 17                // stage 0 = W1/f, stages 1..16 = graph nodes
#define IST 72                   // inpbuf row stride (halves): 144B, 16B-aligned rows
#define WST 68                   // wbuf row stride (halves): 136B -> ~2-way max on b128 reads
#define WBHALF (W64 * WST)       // 4352 halves = 8704 B per weight buffer

typedef _Float16 half4   __attribute__((ext_vector_type(4)));
typedef _Float16 half8   __attribute__((ext_vector_type(8)));
typedef _Float16 half16  __attribute__((ext_vector_type(16)));
typedef float    floatx4 __attribute__((ext_vector_type(4)));
typedef unsigned int uint2v __attribute__((ext_vector_type(2)));

// ================== compile-time graph (np.random.RandomState(0)) ==================
struct GPlan {
    unsigned pred[NN];
    unsigned sinkmask;
    int slot[NSTAGE];            // slot[i]: node i (i<16); slot[16] = f
    int nslot;
};

constexpr unsigned mt_next(unsigned (&mt)[624], int &mti) {
    if (mti >= 624) {
        for (int i = 0; i < 624; ++i) {
            const unsigned y = (mt[i] & 0x80000000u) | (mt[(i + 1) % 624] & 0x7fffffffu);
            unsigned v = mt[(i + 397) % 624] ^ (y >> 1);
            if (y & 1u) v ^= 0x9908b0dfu;
            mt[i] = v;
        }
        mti = 0;
    }
    unsigned y = mt[mti++];
    y ^= y >> 11;
    y ^= (y << 7)  & 0x9d2c5680u;
    y ^= (y << 15) & 0xefc60000u;
    y ^= y >> 18;
    return y;
}
constexpr double mt_rnd(unsigned (&mt)[624], int &mti) {
    const unsigned a = mt_next(mt, mti) >> 5;
    const unsigned b = mt_next(mt, mti) >> 6;
    return (a * 67108864.0 + b) / 9007199254740992.0;
}
constexpr long mt_randint(unsigned (&mt)[624], int &mti, long n) {
    const unsigned long maxv = (unsigned long)n - 1;
    if (maxv == 0) return 0;
    unsigned long mask = maxv;
    mask |= mask >> 1;  mask |= mask >> 2;  mask |= mask >> 4;
    mask |= mask >> 8;  mask |= mask >> 16;
    unsigned long v = (unsigned long)mt_next(mt, mti) & mask;
    while (v > maxv) v = (unsigned long)mt_next(mt, mti) & mask;
    return (long)v;
}

constexpr GPlan build_plan() {
    GPlan P = {};
    unsigned mt[624] = {};
    mt[0] = 0u;
    for (int i = 1; i < 624; ++i)
        mt[i] = 1812433253u * (mt[i-1] ^ (mt[i-1] >> 30)) + (unsigned)i;
    int mti = 624;

    bool edge[NN][NN] = {};
    for (int i = 0; i < NN; ++i) {
        for (int d = 1; d <= 2; ++d) {
            int j = (i + d) & (NN - 1);
            if (mt_rnd(mt, mti) < 0.75) j = (int)mt_randint(mt, mti, NN);
            const int a = i < j ? i : j;
            const int b = i < j ? j : i;
            if (a != b) edge[a][b] = true;
        }
    }
    for (int a = 0; a < NN; ++a)
        for (int b = 0; b < NN; ++b)
            if (edge[a][b]) P.pred[b] |= 1u << a;
    for (int j = 1; j < NN; ++j) {
        if (!P.pred[j]) {
            const int a = (int)mt_randint(mt, mti, j);
            P.pred[j] |= 1u << a;
            edge[a][j] = true;
        }
    }
    unsigned succ[NN] = {};
    for (int a = 0; a < NN; ++a)
        for (int b = 0; b < NN; ++b)
            if (edge[a][b]) succ[a] |= 1u << b;
    for (int j = 0; j < NN; ++j)
        if (!succ[j]) P.sinkmask |= 1u << j;

    int lastuse[NSTAGE] = {};
    for (int v = 0; v < NSTAGE; ++v) lastuse[v] = -1;
    for (int j = 0; j < NN; ++j) {
        const unsigned pm = P.pred[j];
        if (pm == 0u) { if (j > lastuse[16]) lastuse[16] = j; }
        else for (int i = 0; i < NN; ++i)
            if (pm & (1u << i)) { if (j > lastuse[i]) lastuse[i] = j; }
    }
    for (int i = 0; i < NN; ++i)
        if (P.sinkmask & (1u << i)) lastuse[i] = 17;

    int defstage[NSTAGE] = {};
    for (int i = 0; i < NN; ++i) defstage[i] = i + 1;
    defstage[16] = 0;

    int nmax = 0;
    for (int s = 0; s <= 16; ++s) {
        const int w = (s == 0) ? 16 : (s - 1);
        bool busy[NSTAGE] = {};
        for (int v = 0; v < NSTAGE; ++v) {
            if (v == w) continue;
            if (defstage[v] < s && lastuse[v] >= s)
                busy[P.slot[v]] = true;
        }
        int k = 0;
        while (busy[k]) ++k;
        P.slot[w] = k;
        if (k + 1 > nmax) nmax = k + 1;
    }
    P.nslot = nmax;
    return P;
}

constexpr GPlan kPlan = build_plan();
constexpr int NSLOT = kPlan.nslot;

// ---------------- fast activations ----------------
__device__ __forceinline__ float act_tanh(float x)     { return 1.0f - 2.0f / (1.0f + __expf(2.0f * x)); }
__device__ __forceinline__ float act_elu(float x)      { return x > 0.0f ? x : __expf(x) - 1.0f; }
__device__ __forceinline__ float act_softplus(float x) { return fmaxf(x, 0.0f) + __logf(1.0f + __expf(-fabsf(x))); }
__device__ __forceinline__ float act_gauss(float x)    { return __expf(-0.5f * x * x); }

// compile-time activation dispatch (no runtime switch anywhere)
template<int A>
__device__ __forceinline__ float act_c(float x) {
    if constexpr (A == 0)      return act_tanh(x);
    else if constexpr (A == 1) return act_elu(x);
    else if constexpr (A == 2) return act_softplus(x);
    else if constexpr (A == 3) return __sinf(x);
    else                       return act_gauss(x);
}

__device__ __forceinline__ half8 cvt8(float4 a, float4 b) {
    half8 h;
    h[0]=(_Float16)a.x; h[1]=(_Float16)a.y; h[2]=(_Float16)a.z; h[3]=(_Float16)a.w;
    h[4]=(_Float16)b.x; h[5]=(_Float16)b.y; h[6]=(_Float16)b.z; h[7]=(_Float16)b.w;
    return h;
}

// ---------------- weight pre-conversion: fp32 -> fp16 into d_ws ----------------
// ws layout: stage 0 = W1[64][64], stage 1+j = gW[j][64][64]; [w'][k] row-major.
__global__ void convert_weights(const float* __restrict__ W1,
                                const float* __restrict__ gW,
                                _Float16* __restrict__ ws)
{
    const int i = blockIdx.x * 256 + threadIdx.x;
    if (i >= NSTAGE * 4096) return;
    const float v = (i < 4096) ? W1[i] : gW[i - 4096];
    ws[i] = (_Float16)v;
}

// ---------------- weight staging helpers ----------------
// Each thread stages 2x 16B chunks: rows srow=tid>>3 and srow+32, chunk sc8=tid&7.
template<bool F16W, int S>
__device__ __forceinline__ void issue_wload(const _Float16* __restrict__ wsW,
    const float* __restrict__ W1, const float* __restrict__ gW, const int tid,
    uint4& h0, uint4& h1, float4& f0, float4& f1, float4& f2, float4& f3)
{
    if constexpr (F16W) {
        const uint4* src = (const uint4*)(wsW + S * 4096);
        h0 = src[tid];
        h1 = src[tid + 256];
    } else {
        const float* wbase;
        if constexpr (S == 0) wbase = W1; else wbase = gW + (S - 1) * 4096;
        const float4* src = (const float4*)wbase;
        f0 = src[2 * tid];       f1 = src[2 * tid + 1];
        f2 = src[2 * tid + 512]; f3 = src[2 * tid + 513];
    }
}

template<bool F16W>
__device__ __forceinline__ void write_wbuf(_Float16* __restrict__ wb,
    const int srow, const int sc8,
    uint4 h0, uint4 h1, float4 f0, float4 f1, float4 f2, float4 f3)
{
    if constexpr (F16W) {
        *(uint4*)&wb[srow * WST + sc8 * 8]        = h0;
        *(uint4*)&wb[(srow + 32) * WST + sc8 * 8] = h1;
    } else {
        *(half8*)&wb[srow * WST + sc8 * 8]        = cvt8(f0, f1);
        *(half8*)&wb[(srow + 32) * WST + sc8 * 8] = cvt8(f2, f3);
    }
}

// ---------------- one fully-static stage (template S: rule-#20-proof) ----------------
// Double-buffered weight LDS, ONE barrier per stage:
//   stage S: [issue global loads for W_{S+1}] -> read A-frags from wbuf[S&1],
//   MFMA, epilogue, wave-private inpbuf round-trip -> write W_{S+1} into
//   wbuf[(S+1)&1] (vmcnt counted by compiler) -> __syncthreads().
// Parity argument: reads of buf b (stage S+1) and the next overwrite of buf b
// (stage S+2) are separated by the stage-S+1-end barrier, so one barrier suffices.
template<bool F16W, int S>
__device__ __forceinline__ void stage_chain(
    _Float16* __restrict__ wbufA, _Float16* __restrict__ wbufB,
    _Float16* __restrict__ inpbuf, half16* hreg,
    const _Float16* __restrict__ wsW, const float* __restrict__ W1,
    const float* __restrict__ gW, const float* __restrict__ b1,
    const float* __restrict__ gB,
    const int tid, const int rowbase, const int c, const int q,
    const int srow, const int sc8)
{
    _Float16* rb = (S & 1) ? wbufB : wbufA;   // weights for stage S
    _Float16* wb = (S & 1) ? wbufA : wbufB;   // target for stage S+1 weights

    // 1. issue next stage's staging loads — cover = this whole stage body
    uint4 nh0 = {}, nh1 = {};
    float4 nf0 = {}, nf1 = {}, nf2 = {}, nf3 = {};
    if constexpr (S + 1 < NSTAGE)
        issue_wload<F16W, S + 1>(wsW, W1, gW, tid, nh0, nh1, nf0, nf1, nf2, nf3);

    // 2. B-frags from inpbuf (written by previous stage, same wave, in-order)
    const half8 i0 = *(const half8*)&inpbuf[(rowbase + c) * IST +  0 + q * 8];
    const half8 i1 = *(const half8*)&inpbuf[(rowbase + c) * IST + 32 + q * 8];

    const float* bias;
    if constexpr (S == 0) bias = b1; else bias = gB + (S - 1) * W64;

    // 3. A-frags (weight rows) from shared LDS + MFMA; per-t reads keep live
    //    ranges short (VGPR <= 128 target for 4 waves/SIMD)
    floatx4 acc[4];
    #pragma unroll
    for (int t = 0; t < 4; ++t) {
        const half8 wlo = *(const half8*)&rb[(t * 16 + c) * WST +  0 + q * 8];
        const half8 whi = *(const half8*)&rb[(t * 16 + c) * WST + 32 + q * 8];
        const float4 bs = *(const float4*)(bias + t * 16 + q * 4);
        floatx4 z = {bs.x, bs.y, bs.z, bs.w};
        z = __builtin_amdgcn_mfma_f32_16x16x32_f16(wlo, i0, z, 0, 0, 0);
        z = __builtin_amdgcn_mfma_f32_16x16x32_f16(whi, i1, z, 0, 0, 0);
        acc[t] = z;
    }

    // 4. epilogue: activation -> hreg slot (H^T layout); all indices constexpr
    constexpr int an    = (S == 0) ? 3 : ((S - 1) % 5);        // stage0 act = sin
    constexpr int hslot = kPlan.slot[(S == 0) ? 16 : (S - 1)];
    #pragma unroll
    for (int t = 0; t < 4; ++t)
        #pragma unroll
        for (int r = 0; r < 4; ++r)
            hreg[hslot][t * 4 + r] = (_Float16)act_c<an>(acc[t][r]);

    if constexpr (S + 1 < NSTAGE) {
        // 5. next stage's input (packed fp16 pred-sum; masks fold statically)
        constexpr unsigned pm = kPlan.pred[S];
        half16 sum;
        if constexpr (pm == 0u) {                 // source node: input = f
            sum = hreg[kPlan.slot[16]];
        } else {
            #pragma unroll
            for (int v = 0; v < 16; ++v) sum[v] = (_Float16)0.0f;
            #pragma unroll
            for (int i = 0; i < NN; ++i)
                if (pm & (1u << i))               // dead branches removed
                    sum += hreg[kPlan.slot[i]];
        }
        // lane(q,c) owns w' = t*16+q*4..+3 of row rowbase+c: one ds_write_b64 per t
        const uint2v* sp = (const uint2v*)&sum;
        #pragma unroll
        for (int t = 0; t < 4; ++t)
            *(uint2v*)&inpbuf[(rowbase + c) * IST + t * 16 + q * 4] = sp[t];
        // no barrier for inpbuf: same-wave RAW through LDS, in-order per wave

        // 6. land prefetched weights in the other buffer, single barrier
        write_wbuf<F16W>(wb, srow, sc8, nh0, nh1, nf0, nf1, nf2, nf3);
        __syncthreads();

        stage_chain<F16W, S + 1>(wbufA, wbufB, inpbuf, hreg, wsW, W1, gW, b1, gB,
                                 tid, rowbase, c, q, srow, sc8);
    }
}

// ---------------- main fused kernel ----------------
template<bool F16W>
__global__ __launch_bounds__(256, 4) void inr_mfma_kernel(
    const float* __restrict__ inputs, const float* __restrict__ latents,
    const float* __restrict__ Wl, const float* __restrict__ bl,
    const float* __restrict__ Wx, const float* __restrict__ Wy,
    const float* __restrict__ Wr, const float* __restrict__ W1,
    const float* __restrict__ b1, const float* __restrict__ gW,
    const float* __restrict__ gB, const float* __restrict__ outW,
    const float* __restrict__ outb, const float* __restrict__ scale,
    const _Float16* __restrict__ wsW,
    float* __restrict__ out, int Btot)
{
    __shared__ __align__(16) _Float16 wbufA[WBHALF];      // 8704 B
    __shared__ __align__(16) _Float16 wbufB[WBHALF];      // 8704 B
    __shared__ __align__(16) _Float16 inpbuf[MT * IST];   // 9216 B (wave-private rows)

    const int tid  = threadIdx.x;
    const int lane = tid & 63;
    const int wv   = tid >> 6;            // wave id 0..3
    const int q    = lane >> 4;           // quad
    const int c    = lane & 15;           // col-in-tile (= m-row index)
    const int rowbase = wv * 16;          // this wave's 16 M-rows within the tile
    const int m0   = blockIdx.x * MT;
    const int srow = tid >> 3;            // staging row 0..31
    const int sc8  = tid & 7;             // staging chunk-in-row 0..7

    // node state, slot-compressed:
    // hreg[slot][t*4+r] = h_n[m = rowbase+c][w' = t*16 + q*4 + r]
    half16 hreg[NSLOT];

    // ---- prologue: issue stage-0 weight loads, hide them under the embed ----
    uint4 h0 = {}, h1 = {};
    float4 f0 = {}, f1 = {}, f2 = {}, f3 = {};
    issue_wload<F16W, 0>(wsW, W1, gW, tid, h0, h1, f0, f1, f2, f3);

    // ---- embed: g0[m][k] -> inpbuf  (thread t: m = t>>2, k-range = (t&3)*16..+15)
    {
        const int em = tid >> 2, ep = tid & 3;
        int mg = m0 + em; if (mg >= Btot) mg = Btot - 1;
        const float x = inputs[mg * 3 + 0];
        const float y = inputs[mg * 3 + 1];
        const float r = inputs[mg * 3 + 2];
        const float4 l0 = *(const float4*)(latents + mg * 8);
        const float4 l1 = *(const float4*)(latents + mg * 8 + 4);
        half8 hlo, hhi;
        #pragma unroll
        for (int i = 0; i < 16; ++i) {
            const int k = ep * 16 + i;
            const float4 a = *(const float4*)(Wl + k * 8);
            const float4 b = *(const float4*)(Wl + k * 8 + 4);
            float ld = bl[k];
            ld = fmaf(l0.x, a.x, ld); ld = fmaf(l0.y, a.y, ld);
            ld = fmaf(l0.z, a.z, ld); ld = fmaf(l0.w, a.w, ld);
            ld = fmaf(l1.x, b.x, ld); ld = fmaf(l1.y, b.y, ld);
            ld = fmaf(l1.z, b.z, ld); ld = fmaf(l1.w, b.w, ld);
            const float tk = act_tanh(x * Wx[k]) + act_softplus(y * Wy[k])
                           + act_elu(r * Wr[k]) + act_tanh(ld);
            const _Float16 hv = (_Float16)act_gauss(tk);
            if (i < 8) hlo[i] = hv; else hhi[i - 8] = hv;
        }
        *(half8*)&inpbuf[em * IST + ep * 16]     = hlo;   // rows are wave-private
        *(half8*)&inpbuf[em * IST + ep * 16 + 8] = hhi;
    }

    // ---- land stage-0 weights, one barrier, enter the chain ----
    write_wbuf<F16W>(wbufA, srow, sc8, h0, h1, f0, f1, f2, f3);
    __syncthreads();

    stage_chain<F16W, 0>(wbufA, wbufB, inpbuf, hreg, wsW, W1, gW, b1, gB,
                         tid, rowbase, c, q, srow, sc8);

    // ---- head: agg over sinks in-register, reduce over q-lanes, sigmoid ----
    {
        half16 sum;
        #pragma unroll
        for (int v = 0; v < 16; ++v) sum[v] = (_Float16)0.0f;
        #pragma unroll
        for (int j = 0; j < NN; ++j) {
            if (kPlan.sinkmask & (1u << j)) {     // folds statically
                sum += hreg[kPlan.slot[j]];
            }
        }
        float p0 = 0.f, p1 = 0.f, p2 = 0.f;
        #pragma unroll
        for (int t = 0; t < 4; ++t) {
            const float4 w0 = *(const float4*)(outW + 0 * W64 + t * 16 + q * 4);
            const float4 w1 = *(const float4*)(outW + 1 * W64 + t * 16 + q * 4);
            const float4 w2 = *(const float4*)(outW + 2 * W64 + t * 16 + q * 4);
            #pragma unroll
            for (int r = 0; r < 4; ++r) {
                const float av = (float)sum[t * 4 + r];
                p0 = fmaf(av, ((const float*)&w0)[r], p0);
                p1 = fmaf(av, ((const float*)&w1)[r], p1);
                p2 = fmaf(av, ((const float*)&w2)[r], p2);
            }
        }
        // full dot for row m = rowbase+c lives across lanes c, c+16, c+32, c+48
        p0 += __shfl_xor(p0, 16); p0 += __shfl_xor(p0, 32);
        p1 += __shfl_xor(p1, 16); p1 += __shfl_xor(p1, 32);
        p2 += __shfl_xor(p2, 16); p2 += __shfl_xor(p2, 32);
        const int mg = m0 + rowbase + c;
        if (q < 3 && mg < Btot) {
            const float pr  = (q == 0) ? p0 : ((q == 1) ? p1 : p2);
            const float res = (pr + outb[q]) * scale[0];
            out[mg * 3 + q] = 1.0f / (1.0f + __expf(-res));
        }
    }
}

extern "C" void kernel_launch(void* const* d_in, const int* in_sizes, int n_in,
                              void* d_out, int out_size, void* d_ws, size_t ws_size,
                              hipStream_t stream)
{
    const float* inputs  = (const float*)d_in[0];
    const float* latents = (const float*)d_in[1];
    const float* Wl      = (const float*)d_in[2];
    const float* bl      = (const float*)d_in[3];
    const float* Wx      = (const float*)d_in[4];
    const float* Wy      = (const float*)d_in[5];
    const float* Wr      = (const float*)d_in[6];
    const float* W1      = (const float*)d_in[7];
    const float* b1      = (const float*)d_in[8];
    const float* gW      = (const float*)d_in[9];
    const float* gB      = (const float*)d_in[10];
    const float* outW    = (const float*)d_in[11];
    const float* outb    = (const float*)d_in[12];
    const float* scale   = (const float*)d_in[13];
    float* out = (float*)d_out;

    const int Btot = in_sizes[0] / 3;
    const int blocks = (Btot + MT - 1) / MT;
    const size_t wbytes = (size_t)NSTAGE * 4096 * sizeof(_Float16);  // 139264

    if (ws_size >= wbytes) {
        _Float16* wsW = (_Float16*)d_ws;
        convert_weights<<<(NSTAGE * 4096 + 255) / 256, 256, 0, stream>>>(W1, gW, wsW);
        inr_mfma_kernel<true><<<blocks, 256, 0, stream>>>(
            inputs, latents, Wl, bl, Wx, Wy, Wr, W1, b1, gW, gB, outW, outb, scale,
            wsW, out, Btot);
    } else {
        inr_mfma_kernel<false><<<blocks, 256, 0, stream>>>(
            inputs, latents, Wl, bl, Wx, Wy, Wr, W1, b1, gW, gB, outW, outb, scale,
            (const _Float16*)nullptr, out, Btot);
    }
}